// Round 3
// baseline (60725.140 us; speedup 1.0000x reference)
//
#include <hip/hip_runtime.h>
#include <hip/hip_bf16.h>
#include <cstdint>
#include <cstddef>

// ---------------------------------------------------------------------------
// Seq2SeqNet: bidir GRU encoder (1024 steps) + attention GRU greedy decoder
// (256 steps). ALL tensors are fp32 (reference is jnp.float32; harness passes
// float32 -> const float*). All intermediates fp32: greedy argmax feedback
// means low-precision intermediates flip tokens and fail correctness.
// Encoder input-GEMM collapses to a 70-token table; decoder embedding GEMMs
// collapse to 2000-entry tables. Workspace adapts to ws_size by chunking the
// batch: BC=64 needs ~146 MB, 32 -> ~79 MB, 16 -> ~45 MB, 8 -> ~28 MB.
// ---------------------------------------------------------------------------

#define DEV __device__ __forceinline__

constexpr int kH = 512, kH2 = 256, kVC = 2000, kB = 64, kLIN = 1024, kT = 256;
constexpr int kSTART = 1;

// -------------------------------------------------------------------- zero
__global__ __launch_bounds__(256) void k_zero(float* p, int n) {
  int i = blockIdx.x * 256 + threadIdx.x;
  if (i < n) p[i] = 0.f;
}

// ------------------------------------------- encoder input-gate token table
// gi[v][d][j] = bih_d[j] + sum_k emb_jamo[v,k] * Wih_d[j,k]   (j in [0,768))
__global__ __launch_bounds__(256)
void k_gi_table(const float* emb_jamo, const float* Wf, const float* Wb,
                const float* bihf, const float* bihb, float* gi) {
  int v = blockIdx.x >> 1, d = blockIdx.x & 1;
  const float* W = d ? Wb : Wf;
  const float* bih = d ? bihb : bihf;
  __shared__ float x[kH];
  for (int k = threadIdx.x; k < kH; k += 256) x[k] = emb_jamo[v * kH + k];
  __syncthreads();
  for (int j = threadIdx.x; j < 3 * kH2; j += 256) {
    float acc = bih[j];
    const float* row = W + (size_t)j * kH;
    for (int k = 0; k < kH; k += 4) {
      float4 f = *(const float4*)(row + k);
      acc += x[k] * f.x + x[k + 1] * f.y + x[k + 2] * f.z + x[k + 3] * f.w;
    }
    gi[(size_t)(v * 2 + d) * 768 + j] = acc;
  }
}

// ------------------ decoder embedding tables (bias folded):
// A[v][j] = attn_b[j] + emb_char[v] . attn_W[j][0:512]
// C[v][j] = comb_b[j] + emb_char[v] . comb_W[j][0:512]
__global__ __launch_bounds__(256)
void k_ac_emb(const float* emb_char, const float* attn_W, const float* attn_b,
              const float* comb_W, const float* comb_b, float* A, float* C) {
  int v = blockIdx.x;
  __shared__ float x[kH];
  for (int k = threadIdx.x; k < kH; k += 256) x[k] = emb_char[v * kH + k];
  __syncthreads();
  for (int j = threadIdx.x; j < kH; j += 256) {
    float a = attn_b[j], c = comb_b[j];
    const float* ra = attn_W + (size_t)j * 1024;
    const float* rc = comb_W + (size_t)j * 1024;
    for (int k = 0; k < kH; k += 4) {
      float4 fa = *(const float4*)(ra + k), fc = *(const float4*)(rc + k);
      a += x[k] * fa.x + x[k + 1] * fa.y + x[k + 2] * fa.z + x[k + 3] * fa.w;
      c += x[k] * fc.x + x[k + 1] * fc.y + x[k + 2] * fc.z + x[k + 3] * fc.w;
    }
    A[(size_t)v * kH + j] = a;
    C[(size_t)v * kH + j] = c;
  }
}

// ----------------------------------------------------- encoder GRU step
// grid 2*BC blocks; block = (256/BC units) x (BC batches), one dir per block.
__global__ __launch_bounds__(256)
void k_enc_step(const int* tokens, const float* Whf, const float* Whb,
                const float* bhhf, const float* bhhb, const float* gi,
                float* henc, float* enc, int t, int pp, int BC, int lbc, int b0) {
  int d = blockIdx.x >> lbc;
  int blk = blockIdx.x & (BC - 1);
  int b = threadIdx.x & (BC - 1), q = threadIdx.x >> lbc;
  int u = blk * (256 >> lbc) + q;              // hidden unit in [0,256)
  const float* Whh = d ? Whb : Whf;
  const float* bhh = d ? bhhb : bhhf;
  const float* hin = henc + (size_t)(pp * 2 + d) * kH2 * BC;   // [k][b]
  float* hout = henc + (size_t)((1 - pp) * 2 + d) * kH2 * BC;

  const float* wr = Whh + (size_t)(0 * kH2 + u) * kH2;
  const float* wz = Whh + (size_t)(1 * kH2 + u) * kH2;
  const float* wn = Whh + (size_t)(2 * kH2 + u) * kH2;
  float ar = bhh[u], az = bhh[kH2 + u], an = bhh[2 * kH2 + u];
  for (int k = 0; k < kH2; k += 4) {
    float4 fr = *(const float4*)(wr + k);
    float4 fz = *(const float4*)(wz + k);
    float4 fn = *(const float4*)(wn + k);
    float h0v = hin[(k + 0) * BC + b], h1v = hin[(k + 1) * BC + b];
    float h2v = hin[(k + 2) * BC + b], h3v = hin[(k + 3) * BC + b];
    ar += h0v * fr.x + h1v * fr.y + h2v * fr.z + h3v * fr.w;
    az += h0v * fz.x + h1v * fz.y + h2v * fz.z + h3v * fz.w;
    an += h0v * fn.x + h1v * fn.y + h2v * fn.z + h3v * fn.w;
  }
  int v = tokens[(size_t)(b0 + b) * kLIN + t];
  const float* git = gi + (size_t)(v * 2 + d) * 768;
  float r = 1.f / (1.f + expf(-(git[u] + ar)));
  float z = 1.f / (1.f + expf(-(git[kH2 + u] + az)));
  float n = tanhf(git[2 * kH2 + u] + r * an);
  float hprev = hin[u * BC + b];
  float hnew = (1.f - z) * n + z * hprev;
  hout[u * BC + b] = hnew;
  enc[((size_t)b * kLIN + t) * kH + d * kH2 + u] = hnew;
}

// ----------------------------------------------------- decoder prologue
// h0 = enc[b][1023]; key = A[START] + h0 . attn_W[:,512:].T ; tok = START
__global__ __launch_bounds__(256)
void k_prologue(const float* enc, const float* Atab, const float* aW,
                float* hr, float* ht, float* key, int* tok, int BC) {
  int b = blockIdx.x, tid = threadIdx.x;
  __shared__ float h[kH];
  const float* h0 = enc + ((size_t)b * kLIN + (kLIN - 1)) * kH;
  for (int k = tid; k < kH; k += 256) {
    float v = h0[k];
    h[k] = v;
    hr[(size_t)b * kH + k] = v;          // slot 0, row layout [b][k]
    ht[(size_t)k * BC + b] = v;          // slot 0, transposed [k][b]
  }
  if (tid == 0) tok[b] = kSTART;
  __syncthreads();
  const float* A = Atab + (size_t)kSTART * kH;
  for (int j = tid; j < kH; j += 256) {
    const float* row = aW + (size_t)j * 1024 + 512;
    float acc = A[j];
    for (int k = 0; k < kH; k += 4) {
      float4 f = *(const float4*)(row + k);
      acc += h[k] * f.x + h[k + 1] * f.y + h[k + 2] * f.z + h[k + 3] * f.w;
    }
    key[(size_t)b * kH + j] = acc;
  }
}

// ------------- scores + per-tile softmax partials + per-tile ctx partials
// grid BC*8 = (b, l-tile of 128). Half-wave (32 lanes) computes one score.
__global__ __launch_bounds__(256)
void k_scores(const float* encAll, const float* keyAll, float* sc,
              float* pm, float* pd, float* pctx) {
  int b = blockIdx.x >> 3, lt = blockIdx.x & 7;
  int tid = threadIdx.x, lane = tid & 63, w = tid >> 6, hl = lane & 31, half = lane >> 5;
  __shared__ float s_tile[128], e_tile[128], red[128];
  const float* enc = encAll + (size_t)b * kLIN * kH;
  float kreg[16];
  const float* key = keyAll + (size_t)b * kH + hl * 16;
#pragma unroll
  for (int m = 0; m < 16; m += 4) *(float4*)(kreg + m) = *(const float4*)(key + m);
  for (int i = 0; i < 16; i++) {
    int ll = w * 32 + i * 2 + half;
    int l = lt * 128 + ll;
    const float* row = enc + (size_t)l * kH + hl * 16;
    float acc = 0.f;
#pragma unroll
    for (int m = 0; m < 16; m += 4) {
      float4 v = *(const float4*)(row + m);
      acc += v.x * kreg[m] + v.y * kreg[m + 1] + v.z * kreg[m + 2] + v.w * kreg[m + 3];
    }
#pragma unroll
    for (int m2 = 16; m2 > 0; m2 >>= 1) acc += __shfl_xor(acc, m2, 32);
    if (hl == 0) { s_tile[ll] = acc; sc[(size_t)b * kLIN + l] = acc; }
  }
  __syncthreads();
  if (tid < 128) red[tid] = s_tile[tid];
  __syncthreads();
  for (int s = 64; s > 0; s >>= 1) {
    if (tid < s) red[tid] = fmaxf(red[tid], red[tid + s]);
    __syncthreads();
  }
  float mt = red[0];
  __syncthreads();
  if (tid < 128) { e_tile[tid] = expf(s_tile[tid] - mt); red[tid] = e_tile[tid]; }
  __syncthreads();
  for (int s = 64; s > 0; s >>= 1) {
    if (tid < s) red[tid] += red[tid + s];
    __syncthreads();
  }
  float dt = red[0];
  int h0i = tid * 2;
  float cx = 0.f, cy = 0.f;
  const float* base = enc + (size_t)(lt * 128) * kH + h0i;
  for (int l = 0; l < 128; l++) {
    float e = e_tile[l];
    float2 v = *(const float2*)(base + (size_t)l * kH);
    cx += e * v.x; cy += e * v.y;
  }
  float* pc = pctx + ((size_t)b * 8 + lt) * kH;
  pc[h0i] = cx; pc[h0i + 1] = cy;
  if (tid == 0) { pm[b * 8 + lt] = mt; pd[b * 8 + lt] = dt; }
}

// ---- combine partials -> ctx, write attention weights, g = relu(C[tok]+ctx.Wc)
__global__ __launch_bounds__(256)
void k_ctx_g(const float* cW, const float* Ctab, const float* sc,
             const float* pm, const float* pd, const float* pctx,
             const int* tok, float* out1, float* gt, int BC, int b0, int t) {
  int b = blockIdx.x, tid = threadIdx.x;
  __shared__ float f8[8], MD[2], ctxl[kH];
  __shared__ int tokl;
  if (tid == 0) {
    float M = -1e30f;
    for (int i = 0; i < 8; i++) M = fmaxf(M, pm[b * 8 + i]);
    float D = 0.f;
    for (int i = 0; i < 8; i++) {
      float f = expf(pm[b * 8 + i] - M);
      f8[i] = f; D += f * pd[b * 8 + i];
    }
    MD[0] = M; MD[1] = 1.f / D;
    tokl = tok[b];
  }
  __syncthreads();
  float M = MD[0], invD = MD[1];
  int h0i = tid * 2;
  float cx = 0.f, cy = 0.f;
  for (int i = 0; i < 8; i++) {
    const float* pc = pctx + ((size_t)b * 8 + i) * kH + h0i;
    cx += f8[i] * pc[0]; cy += f8[i] * pc[1];
  }
  ctxl[h0i] = cx * invD; ctxl[h0i + 1] = cy * invD;
  int gb = b0 + b;
  for (int l = tid; l < kLIN; l += 256)
    out1[((size_t)gb * kLIN + l) * kT + t] = expf(sc[(size_t)b * kLIN + l] - M) * invD;
  __syncthreads();
  int tk = tokl;
  for (int j = tid; j < kH; j += 256) {
    const float* row = cW + (size_t)j * 1024 + 512;
    float acc = Ctab[(size_t)tk * kH + j];
    for (int k = 0; k < kH; k += 4) {
      float4 f = *(const float4*)(row + k);
      acc += ctxl[k] * f.x + ctxl[k + 1] * f.y + ctxl[k + 2] * f.z + ctxl[k + 3] * f.w;
    }
    gt[(size_t)j * BC + b] = fmaxf(acc, 0.f);
  }
}

// --------------------------- decoder GRU: thread per (u, b), full 512 dots
__global__ __launch_bounds__(256)
void k_gru(const float* Wih, const float* Whh, const float* bih, const float* bhh,
           const float* gt, float* ht, float* hr, int BC, int lbc, int pp) {
  int tid = threadIdx.x;
  int b = tid & (BC - 1), q = tid >> lbc;
  int u = blockIdx.x * (256 >> lbc) + q;        // [0,512)
  const float* htp = ht + (size_t)pp * kH * BC;
  float air = bih[u], aiz = bih[kH + u], ain = bih[2 * kH + u];
  float ahr = bhh[u], ahz = bhh[kH + u], ahn = bhh[2 * kH + u];
  const float* wir = Wih + (size_t)(0 * kH + u) * kH;
  const float* wiz = Wih + (size_t)(1 * kH + u) * kH;
  const float* win = Wih + (size_t)(2 * kH + u) * kH;
  const float* whr = Whh + (size_t)(0 * kH + u) * kH;
  const float* whz = Whh + (size_t)(1 * kH + u) * kH;
  const float* whn = Whh + (size_t)(2 * kH + u) * kH;
  for (int k = 0; k < kH; k += 4) {
    float4 fir = *(const float4*)(wir + k), fiz = *(const float4*)(wiz + k), fin = *(const float4*)(win + k);
    float4 fhr = *(const float4*)(whr + k), fhz = *(const float4*)(whz + k), fhn = *(const float4*)(whn + k);
    float g0 = gt[(k + 0) * BC + b], g1 = gt[(k + 1) * BC + b];
    float g2 = gt[(k + 2) * BC + b], g3 = gt[(k + 3) * BC + b];
    float h0v = htp[(k + 0) * BC + b], h1v = htp[(k + 1) * BC + b];
    float h2v = htp[(k + 2) * BC + b], h3v = htp[(k + 3) * BC + b];
    air += g0 * fir.x + g1 * fir.y + g2 * fir.z + g3 * fir.w;
    aiz += g0 * fiz.x + g1 * fiz.y + g2 * fiz.z + g3 * fiz.w;
    ain += g0 * fin.x + g1 * fin.y + g2 * fin.z + g3 * fin.w;
    ahr += h0v * fhr.x + h1v * fhr.y + h2v * fhr.z + h3v * fhr.w;
    ahz += h0v * fhz.x + h1v * fhz.y + h2v * fhz.z + h3v * fhz.w;
    ahn += h0v * fhn.x + h1v * fhn.y + h2v * fhn.z + h3v * fhn.w;
  }
  float r = 1.f / (1.f + expf(-(air + ahr)));
  float z = 1.f / (1.f + expf(-(aiz + ahz)));
  float n = tanhf(ain + r * ahn);
  float hp = htp[(size_t)u * BC + b];
  float hnew = (1.f - z) * n + z * hp;
  ht[(size_t)(1 - pp) * kH * BC + (size_t)u * BC + b] = hnew;
  hr[(size_t)(1 - pp) * BC * kH + (size_t)b * kH + u] = hnew;
}

// ----------------------------- logits: grid BC*8 = (b, c-tile of 250)
__global__ __launch_bounds__(256)
void k_logits(const float* oW, const float* ob, const float* hr, float* lg,
              int BC, int np) {
  int b = blockIdx.x >> 3, ct = blockIdx.x & 7;
  int tid = threadIdx.x, lane = tid & 63, w = tid >> 6, hl = lane & 31, half = lane >> 5;
  const float* hrow = hr + (size_t)np * BC * kH + (size_t)b * kH + hl * 16;
  float hreg[16];
#pragma unroll
  for (int m = 0; m < 16; m += 4) *(float4*)(hreg + m) = *(const float4*)(hrow + m);
  int c0 = ct * 250;
  for (int i = 0; i < 32; i++) {
    int c = c0 + i * 8 + w * 2 + half;
    if (c < c0 + 250) {
      const float* row = oW + (size_t)c * kH + hl * 16;
      float acc = 0.f;
#pragma unroll
      for (int m = 0; m < 16; m += 4) {
        float4 v = *(const float4*)(row + m);
        acc += v.x * hreg[m] + v.y * hreg[m + 1] + v.z * hreg[m + 2] + v.w * hreg[m + 3];
      }
#pragma unroll
      for (int m2 = 16; m2 > 0; m2 >>= 1) acc += __shfl_xor(acc, m2, 32);
      if (hl == 0) lg[(size_t)b * kVC + c] = acc + ob[c];
    }
  }
}

// ---- log_softmax + out0 + argmax (np semantics) + loss + next-step key
__global__ __launch_bounds__(256)
void k_finish(const float* aW, const int* targets, const float* mask,
              const float* Atab, const float* hr, const float* lg,
              float* key, int* tok, float* loss, float* out0,
              int BC, int b0, int t, int np) {
  int b = blockIdx.x, tid = threadIdx.x, gb = b0 + b;
  __shared__ float rv[256]; __shared__ int ri[256]; __shared__ float rs[256];
  __shared__ float hsh[kH];
  const float* lrow = lg + (size_t)b * kVC;
  float xv[8];
  float bv = -3.4e38f; int bi = kVC;
#pragma unroll
  for (int i = 0; i < 8; i++) {
    int c = tid + i * 256;
    float x = (c < kVC) ? lrow[c] : -3.4e38f;
    xv[i] = x;
    if (x > bv) { bv = x; bi = c; }
  }
  rv[tid] = bv; ri[tid] = bi;
  __syncthreads();
  for (int s = 128; s > 0; s >>= 1) {
    if (tid < s) {
      float v2 = rv[tid + s]; int i2 = ri[tid + s];
      if (v2 > rv[tid] || (v2 == rv[tid] && i2 < ri[tid])) { rv[tid] = v2; ri[tid] = i2; }
    }
    __syncthreads();
  }
  float M = rv[0]; int nt = ri[0];
  float se = 0.f;
#pragma unroll
  for (int i = 0; i < 8; i++) { int c = tid + i * 256; if (c < kVC) se += expf(xv[i] - M); }
  rs[tid] = se;
  __syncthreads();
  for (int s = 128; s > 0; s >>= 1) {
    if (tid < s) rs[tid] += rs[tid + s];
    __syncthreads();
  }
  float lse = M + logf(rs[0]);
  float* orow = out0 + ((size_t)gb * kT + t) * kVC;
#pragma unroll
  for (int i = 0; i < 8; i++) { int c = tid + i * 256; if (c < kVC) orow[c] = xv[i] - lse; }
  if (tid == 0) {
    tok[b] = nt;
    int tg = targets[(size_t)gb * kT + t];
    float mk = mask[(size_t)gb * kT + t];
    atomicAdd(loss, (lse - lrow[tg]) * mk * (1.f / 16384.f));  // /B /T
  }
  // next key: key[b][j] = A[nt][j] + h_new[b] . attn_W[j][512:1024]
  const float* hrow = hr + (size_t)np * BC * kH + (size_t)b * kH;
  for (int k = tid; k < kH; k += 256) hsh[k] = hrow[k];
  __syncthreads();
  const float* A = Atab + (size_t)nt * kH;
  for (int j = tid; j < kH; j += 256) {
    const float* row = aW + (size_t)j * 1024 + 512;
    float acc = A[j];
    for (int k = 0; k < kH; k += 4) {
      float4 f = *(const float4*)(row + k);
      acc += hsh[k] * f.x + hsh[k + 1] * f.y + hsh[k + 2] * f.z + hsh[k + 3] * f.w;
    }
    key[(size_t)b * kH + j] = acc;
  }
}

__global__ void k_loss_out(float* dst, const float* loss) {
  if (threadIdx.x == 0 && blockIdx.x == 0) *dst = *loss;
}

// ---------------------------------------------------------------------------
extern "C" void kernel_launch(void* const* d_in, const int* in_sizes, int n_in,
                              void* d_out, int out_size, void* d_ws, size_t ws_size,
                              hipStream_t stream) {
  (void)in_sizes; (void)n_in;
  const int*   tok_in = (const int*)d_in[0];
  const int*   tgt    = (const int*)d_in[1];
  const float* mask   = (const float*)d_in[2];
  const float* emb_j  = (const float*)d_in[3];
  const float* emb_c  = (const float*)d_in[4];
  const float* eWif   = (const float*)d_in[5];
  const float* eWhf   = (const float*)d_in[6];
  const float* ebif   = (const float*)d_in[7];
  const float* ebhf   = (const float*)d_in[8];
  const float* eWib   = (const float*)d_in[9];
  const float* eWhb   = (const float*)d_in[10];
  const float* ebib   = (const float*)d_in[11];
  const float* ebhb   = (const float*)d_in[12];
  const float* dWi    = (const float*)d_in[13];
  const float* dWh    = (const float*)d_in[14];
  const float* dbi    = (const float*)d_in[15];
  const float* dbh    = (const float*)d_in[16];
  const float* aW     = (const float*)d_in[17];
  const float* ab     = (const float*)d_in[18];
  const float* cW     = (const float*)d_in[19];
  const float* cb     = (const float*)d_in[20];
  const float* oW     = (const float*)d_in[21];
  const float* ob     = (const float*)d_in[22];
  float* ws   = (float*)d_ws;
  float* out0 = (float*)d_out;
  float* out1 = out0 + (size_t)kB * kT * kVC;

  // ---- workspace layout (floats); small state sized for BC=64 capacity
  const size_t GI = 0;
  const size_t A  = GI + 107520;            // 70*2*768
  const size_t C  = A + 1024000;            // 2000*512
  const size_t SMALL = C + 1024000;
  size_t o = SMALL;
  const size_t HENC = o; o += 4 * 256 * 64; // [2pp][2dir][256][BC]
  const size_t KEY  = o; o += 64 * 512;
  const size_t SC   = o; o += 64 * 1024;
  const size_t PM   = o; o += 512;
  const size_t PD   = o; o += 512;
  const size_t PCT  = o; o += 64 * 8 * 512;
  const size_t GT   = o; o += 512 * 64;
  const size_t HR   = o; o += 2 * 64 * 512;
  const size_t HT   = o; o += 2 * 512 * 64;
  const size_t LG   = o; o += 64 * 2000;
  const size_t TOKo = o; o += 64;
  const size_t LOSS = o; o += 1;
  const size_t ENC  = o;                    // + BC*1024*512
  const int small_n = (int)(ENC - SMALL);

  // largest batch-chunk BC that fits ws_size (constant across calls ->
  // identical launch sequence every call; graph-capture safe)
  int BC = 64;
  while (BC > 8 && (ENC + (size_t)BC * kLIN * kH) * sizeof(float) > ws_size) BC >>= 1;
  int lbc = (BC == 64) ? 6 : (BC == 32) ? 5 : (BC == 16) ? 4 : 3;
  int NC = kB / BC;
  int* tokp = (int*)(ws + TOKo);

  k_zero<<<(small_n + 255) / 256, 256, 0, stream>>>(ws + SMALL, small_n);
  k_gi_table<<<140, 256, 0, stream>>>(emb_j, eWif, eWib, ebif, ebib, ws + GI);
  k_ac_emb<<<2000, 256, 0, stream>>>(emb_c, aW, ab, cW, cb, ws + A, ws + C);

  for (int c = 0; c < NC; c++) {
    int b0 = c * BC;
    k_zero<<<(4 * 256 * BC + 255) / 256, 256, 0, stream>>>(ws + HENC, 4 * 256 * BC);
    for (int t = 0; t < kLIN; t++)
      k_enc_step<<<2 * BC, 256, 0, stream>>>(tok_in, eWhf, eWhb, ebhf, ebhb,
                                             ws + GI, ws + HENC, ws + ENC,
                                             t, t & 1, BC, lbc, b0);
    k_prologue<<<BC, 256, 0, stream>>>(ws + ENC, ws + A, aW, ws + HR, ws + HT,
                                       ws + KEY, tokp, BC);
    for (int t = 0; t < kT; t++) {
      int pp = t & 1, np = 1 - pp;
      k_scores<<<BC * 8, 256, 0, stream>>>(ws + ENC, ws + KEY, ws + SC,
                                           ws + PM, ws + PD, ws + PCT);
      k_ctx_g<<<BC, 256, 0, stream>>>(cW, ws + C, ws + SC, ws + PM, ws + PD,
                                      ws + PCT, tokp, out1, ws + GT, BC, b0, t);
      k_gru<<<2 * BC, 256, 0, stream>>>(dWi, dWh, dbi, dbh, ws + GT,
                                        ws + HT, ws + HR, BC, lbc, pp);
      k_logits<<<BC * 8, 256, 0, stream>>>(oW, ob, ws + HR, ws + LG, BC, np);
      k_finish<<<BC, 256, 0, stream>>>(aW, tgt, mask, ws + A, ws + HR, ws + LG,
                                       ws + KEY, tokp, ws + LOSS, out0,
                                       BC, b0, t, np);
    }
  }
  k_loss_out<<<1, 64, 0, stream>>>(out0 + (size_t)out_size - 1, ws + LOSS);
}